// Round 13
// baseline (1149.402 us; speedup 1.0000x reference)
//
#include <hip/hip_runtime.h>

#define TT 4096
#define BB 128
#define L2E 1.4426950408889634f

typedef unsigned uv2 __attribute__((ext_vector_type(2)));
typedef float v2f __attribute__((ext_vector_type(2)));

__device__ __forceinline__ float fexp2(float a) { return __builtin_amdgcn_exp2f(a); }

__device__ __forceinline__ float bpermf(int idx_bytes, float v) {
  return __int_as_float(__builtin_amdgcn_ds_bpermute(idx_bytes, __float_as_int(v)));
}

// (fallback kernel only)
__device__ __forceinline__ float xhalf_sum(float p) {
#if __has_builtin(__builtin_amdgcn_permlane32_swap)
  uv2 r = __builtin_amdgcn_permlane32_swap(__float_as_uint(p), __float_as_uint(p),
                                           false, false);
  return __uint_as_float(r[0]) + __uint_as_float(r[1]);
#else
  return p + bpermf((threadIdx.x ^ 32) << 2, p);
#endif
}

__device__ __forceinline__ unsigned long long hpair(float h, int k) {
  unsigned lo = (unsigned)__builtin_amdgcn_readlane(__float_as_int(h), k);
  unsigned hi = (unsigned)__builtin_amdgcn_readlane(__float_as_int(h), k + 1);
  return (unsigned long long)lo | ((unsigned long long)hi << 32);
}

__device__ __forceinline__ void pkfma(v2f& acc, v2f w, unsigned long long hs) {
  asm("v_pk_fma_f32 %0, %1, %2, %0" : "+v"(acc) : "v"(w), "s"(hs));
}

// gx[b,t,g]: g<64  -> L2E*(x.w_ih[g] + b_ih[g] + b_hh[g])   (r,z pre-activation)
//            g>=64 -> 2*L2E*(x.w_ih[g] + b_ih[g])           (n x-side)
__global__ __launch_bounds__(256) void gx_pre(
    const float* __restrict__ x, const float* __restrict__ w_ih,
    const float* __restrict__ b_ih, const float* __restrict__ b_hh,
    const int* __restrict__ lengths, float* __restrict__ gx) {
  const size_t idx = (size_t)blockIdx.x * 256 + threadIdx.x;  // (b*T+t)*96+g
  const int g = (int)(idx % 96);
  const size_t bt = idx / 96;
  const int b = (int)(bt >> 12);
  const int t = (int)(bt & (TT - 1));
  if (t >= lengths[b]) return;
  const float* xp = x + bt * 6;
  float acc = (g < 64) ? (b_ih[g] + b_hh[g]) : b_ih[g];
#pragma unroll
  for (int i = 0; i < 6; ++i) acc = fmaf(w_ih[g * 6 + i], xp[i], acc);
  gx[idx] = (g < 64) ? (L2E * acc) : (2.0f * L2E * acc);
}

// One wave per batch element, gate-packed halves:
//   lane l (j=l&31): A-gate = r-row j (l<32) or z-row j (l>=32); B-gate = n-row j.
// One 16-pkfma block + one exp2+rcp computes BOTH sigmoids (r in half0, z in
// half1); z crosses back via one ds_bpermute whose latency hides under the
// tanh chain. Half1's h is garbage after `ap` — never read (readlane sources
// are lanes 0-31; LDS ring store masked to lanes<32).
__global__ __launch_bounds__(64) __attribute__((amdgpu_waves_per_eu(1, 1)))
void gru_seq(const int* __restrict__ lengths, const float* __restrict__ w_hh,
             const float* __restrict__ b_hh, const float* __restrict__ gx,
             float* __restrict__ hbuf) {
  __shared__ alignas(16) float hring[2][32][32];  // buf, step, j = 8 KB

  const int b = blockIdx.x;
  const int l = threadIdx.x;
  const int j = l & 31;
  const bool half0 = (l < 32);
  const int len = lengths[b];

  // A rows: r (half0) / z (half1), pre-scaled L2E; B rows: n, pre-scaled 2*L2E
  v2f wA2[16], wB2[16];
  {
    const v2f* pA = (const v2f*)(w_hh + ((half0 ? 0 : 32) + j) * 32);
    const v2f* pB = (const v2f*)(w_hh + (64 + j) * 32);
#pragma unroll
    for (int k = 0; k < 16; ++k) wA2[k] = pA[k] * L2E;
#pragma unroll
    for (int k = 0; k < 16; ++k) wB2[k] = pB[k] * (2.0f * L2E);
  }
  const float bhn = 2.0f * L2E * b_hh[64 + j];

  const float* gxb = gx + (size_t)b * TT * 96;
  const int offA = (half0 ? 0 : 32) + j;  // r-part or z-part of gx
  const int offB = 64 + j;                // n x-part
  float* hrow = hbuf + (size_t)b * TT * 32;
  const int pswap = (l ^ 32) << 2;  // bpermute byte index: partner half

  float h = 0.0f;
  int t = 0;

  // 4-deep gx prefetch slots (named scalars; static indexing)
  float g0a, g0b, g1a, g1b, g2a, g2b, g3a, g3b;
  {
    const int t1 = (1 < len) ? 1 : len - 1, t2 = (2 < len) ? 2 : len - 1,
              t3 = (3 < len) ? 3 : len - 1;
    const float *p0 = gxb, *p1 = gxb + (size_t)t1 * 96,
                *p2 = gxb + (size_t)t2 * 96, *p3 = gxb + (size_t)t3 * 96;
    g0a = p0[offA]; g0b = p0[offB];
    g1a = p1[offA]; g1b = p1[offB];
    g2a = p2[offA]; g2b = p2[offB];
    g3a = p3[offA]; g3b = p3[offB];
  }

  auto flush = [&](int base, int cnt) {
    const float4* src = (const float4*)(&hring[(base >> 5) & 1][0][0]);
    float4* dst = (float4*)(hrow + (size_t)base * 32);
    const int n4 = cnt * 8;
    for (int q = l; q < n4; q += 64) dst[q] = src[q];
  };

  auto step = [&](float& GA, float& GB) {
    const float xA_ = GA, xB_ = GB;
    // refill this slot for t+4 (independent; max slack)
    {
      const int tp = (t + 4 < len) ? (t + 4) : (len - 1);
      const float* gp = gxb + (size_t)tp * 96;
      GA = gp[offA];
      GB = gp[offB];
    }

    // broadcast h as 16 SGPR pairs (lanes 0-31 hold valid h)
    unsigned long long hp[16];
#pragma unroll
    for (int i = 0; i < 16; ++i) hp[i] = hpair(h, 2 * i);

    // A-dots: r (half0) and z (half1) in one 16-pkfma block
    v2f aA0 = {xA_, 0.f}, aA1 = {0.f, 0.f};
#pragma unroll
    for (int k = 0; k < 8; ++k) {
      pkfma(aA0, wA2[k], hp[k]);
      pkfma(aA1, wA2[k + 8], hp[k + 8]);
    }
    const v2f aAs = aA0 + aA1;
    const float sA = aAs[0] + aAs[1];  // already *L2E
    const float eA = fexp2(-sA);       // trans-pipe; B-dots fill its latency

    // B-dots: n hidden part (both halves identical)
    v2f aB0 = {bhn, 0.f}, aB1 = {0.f, 0.f};
#pragma unroll
    for (int k = 0; k < 8; ++k) {
      pkfma(aB0, wB2[k], hp[k]);
      pkfma(aB1, wB2[k + 8], hp[k + 8]);
    }
    const v2f aBs = aB0 + aB1;
    const float hn = aBs[0] + aBs[1];  // already *2L2E (incl bhn)

    const float rs = __builtin_amdgcn_rcpf(1.0f + eA);  // r (half0) / z (half1)
    const float zv = bpermf(pswap, rs);  // z -> lane j; latency hides under tanh
    const float ap = fmaf(rs, hn, xB_);  // half1 computes garbage from here on
    const float qq = __builtin_amdgcn_rcpf(1.0f + fexp2(-ap));
    const float nn = fmaf(2.0f, qq, -1.0f);
    h = fmaf(zv, h - nn, nn);

    if (half0) hring[(t >> 5) & 1][t & 31][j] = h;
    if ((t & 31) == 31) flush(t - 31, 32);
    ++t;
  };

  while (t + 4 <= len) {
    step(g0a, g0b);
    step(g1a, g1b);
    step(g2a, g2b);
    step(g3a, g3b);
  }
  if (t < len) step(g0a, g0b);
  if (t < len) step(g1a, g1b);
  if (t < len) step(g2a, g2b);

  const int rem = len & 31;
  if (rem) flush(len - rem, rem);
}

// out[b,t,:] = (t < len[b]) ? h[b,t,:] @ fc_w^T + fc_b : fc_b
__global__ __launch_bounds__(256) void fc_apply(
    const float* __restrict__ hbuf, const int* __restrict__ lengths,
    const float* __restrict__ fc_w, const float* __restrict__ fc_b,
    float* __restrict__ out) {
  const int idx = blockIdx.x * 256 + threadIdx.x;  // flattened (b,t)
  const int b = idx >> 12;
  const int t = idx & (TT - 1);
  const float fb0 = fc_b[0], fb1 = fc_b[1];
  float* op = out + (size_t)idx * 2;
  if (t >= lengths[b]) {
    op[0] = fb0;
    op[1] = fb1;
    return;
  }
  const float4* hp = (const float4*)(hbuf + (size_t)idx * 32);
  const float4* w0 = (const float4*)(fc_w);
  const float4* w1 = (const float4*)(fc_w + 32);
  float o0 = 0.f, o1 = 0.f;
#pragma unroll
  for (int q = 0; q < 8; ++q) {
    const float4 hv = hp[q], a = w0[q], c = w1[q];
    o0 += hv.x * a.x + hv.y * a.y + hv.z * a.z + hv.w * a.w;
    o1 += hv.x * c.x + hv.y * c.y + hv.z * c.z + hv.w * c.w;
  }
  op[0] = o0 + fb0;
  op[1] = o1 + fb1;
}

// Fallback (ws too small): self-contained single kernel (R6 structure).
__global__ __launch_bounds__(64) void gru_fallback(
    const float* __restrict__ x, const int* __restrict__ lengths,
    const float* __restrict__ w_ih, const float* __restrict__ w_hh,
    const float* __restrict__ b_ih, const float* __restrict__ b_hh,
    const float* __restrict__ fc_w, const float* __restrict__ fc_b,
    float* __restrict__ out) {
  const int b = blockIdx.x;
  const int l = threadIdx.x;
  const int j = l & 31;
  const int half = l >> 5;
  const int ko = half << 4;
  const int len = lengths[b];

  float wr[16], wz[16], wn[16];
#pragma unroll
  for (int k = 0; k < 16; ++k) wr[k] = w_hh[j * 32 + ko + k] * L2E;
#pragma unroll
  for (int k = 0; k < 16; ++k) wz[k] = w_hh[(32 + j) * 32 + ko + k] * L2E;
#pragma unroll
  for (int k = 0; k < 16; ++k) wn[k] = w_hh[(64 + j) * 32 + ko + k] * (2.0f * L2E);
  float wxr[6], wxz[6], wxn[6];
#pragma unroll
  for (int i = 0; i < 6; ++i) wxr[i] = w_ih[j * 6 + i] * (0.5f * L2E);
#pragma unroll
  for (int i = 0; i < 6; ++i) wxz[i] = w_ih[(32 + j) * 6 + i] * (0.5f * L2E);
#pragma unroll
  for (int i = 0; i < 6; ++i) wxn[i] = w_ih[(64 + j) * 6 + i] * (2.0f * L2E);
  const float br = (b_ih[j] + b_hh[j]) * (0.5f * L2E);
  const float bz = (b_ih[32 + j] + b_hh[32 + j]) * (0.5f * L2E);
  const float bxn = b_ih[64 + j] * (2.0f * L2E);
  const float bhn = b_hh[64 + j] * L2E;
  const float fcw = fc_w[half * 32 + j];
  const float fcb = fc_b[half];

  const float* xb = x + (size_t)b * (TT * 6);
  float* ob = out + (size_t)b * (TT * 2);
  const int bko = half << 6;
  float h = 0.0f;

  v2f cx[3], nx[3];
  {
    const v2f* xp = (const v2f*)xb;
    cx[0] = xp[0]; cx[1] = xp[1]; cx[2] = xp[2];
  }
  for (int t = 0; t < len; ++t) {
    const int tn = (t + 1 < len) ? (t + 1) : t;
    const v2f* xp = (const v2f*)(xb + tn * 6);
    nx[0] = xp[0]; nx[1] = xp[1]; nx[2] = xp[2];
    float xr = br, xz = bz, xn = bxn;
#pragma unroll
    for (int i = 0; i < 3; ++i) {
      const float c0 = cx[i][0], c1 = cx[i][1];
      xr = fmaf(wxr[2 * i], c0, xr); xr = fmaf(wxr[2 * i + 1], c1, xr);
      xz = fmaf(wxz[2 * i], c0, xz); xz = fmaf(wxz[2 * i + 1], c1, xz);
      xn = fmaf(wxn[2 * i], c0, xn); xn = fmaf(wxn[2 * i + 1], c1, xn);
    }
    float hbv[16];
#pragma unroll
    for (int k = 0; k < 16; ++k) hbv[k] = bpermf(bko + (k << 2), h);
    float ar0 = xr, ar1 = 0.f, az0 = xz, az1 = 0.f, an0 = bhn, an1 = 0.f;
#pragma unroll
    for (int k = 0; k < 8; ++k) {
      ar0 = fmaf(wr[k], hbv[k], ar0);
      ar1 = fmaf(wr[k + 8], hbv[k + 8], ar1);
      az0 = fmaf(wz[k], hbv[k], az0);
      az1 = fmaf(wz[k + 8], hbv[k + 8], az1);
      an0 = fmaf(wn[k], hbv[k], an0);
      an1 = fmaf(wn[k + 8], hbv[k + 8], an1);
    }
    const float sr = xhalf_sum(ar0 + ar1);
    const float r = __builtin_amdgcn_rcpf(1.0f + fexp2(-sr));
    const float sz = xhalf_sum(az0 + az1);
    const float z = __builtin_amdgcn_rcpf(1.0f + fexp2(-sz));
    const float hn = xhalf_sum(an0 + an1);
    const float ap = fmaf(r, hn, xn);
    const float qq = __builtin_amdgcn_rcpf(1.0f + fexp2(-ap));
    const float nn = fmaf(2.0f, qq, -1.0f);
    h = fmaf(z, h - nn, nn);
    float p = h * fcw;
    p += __shfl_xor(p, 1);
    p += __shfl_xor(p, 2);
    p += __shfl_xor(p, 4);
    p += __shfl_xor(p, 8);
    p += __shfl_xor(p, 16);
    if (j == 0) ob[t * 2 + half] = p + fcb;
#pragma unroll
    for (int i = 0; i < 3; ++i) cx[i] = nx[i];
  }
  const float fb0 = fc_b[0], fb1 = fc_b[1];
  for (int idx = len * 2 + l; idx < TT * 2; idx += 64)
    ob[idx] = (idx & 1) ? fb1 : fb0;
}

extern "C" void kernel_launch(void* const* d_in, const int* in_sizes, int n_in,
                              void* d_out, int out_size, void* d_ws, size_t ws_size,
                              hipStream_t stream) {
  const float* x       = (const float*)d_in[0];
  const int*   lengths = (const int*)d_in[1];
  const float* w_ih    = (const float*)d_in[2];
  const float* w_hh    = (const float*)d_in[3];
  const float* b_ih    = (const float*)d_in[4];
  const float* b_hh    = (const float*)d_in[5];
  const float* fc_w    = (const float*)d_in[6];
  const float* fc_b    = (const float*)d_in[7];
  float* outp = (float*)d_out;

  const size_t hbuf_elems = (size_t)BB * TT * 32;               // 64 MB
  const size_t gx_elems   = (size_t)BB * TT * 96;               // 192 MB
  const size_t need = (hbuf_elems + gx_elems) * sizeof(float);  // 256 MB
  if (ws_size >= need) {
    float* hbuf = (float*)d_ws;
    float* gx = (float*)d_ws + hbuf_elems;
    hipLaunchKernelGGL(gx_pre, dim3((BB * TT * 96) / 256), dim3(256), 0, stream,
                       x, w_ih, b_ih, b_hh, lengths, gx);
    hipLaunchKernelGGL(gru_seq, dim3(BB), dim3(64), 0, stream,
                       lengths, w_hh, b_hh, gx, hbuf);
    hipLaunchKernelGGL(fc_apply, dim3((BB * TT) / 256), dim3(256), 0, stream,
                       hbuf, lengths, fc_w, fc_b, outp);
  } else {
    hipLaunchKernelGGL(gru_fallback, dim3(BB), dim3(64), 0, stream,
                       x, lengths, w_ih, w_hh, b_ih, b_hh, fc_w, fc_b, outp);
  }
}

// Round 14
// 863.151 us; speedup vs baseline: 1.3316x; 1.3316x over previous
//
#include <hip/hip_runtime.h>

#define TT 4096
#define BB 128
#define L2E 1.4426950408889634f

typedef unsigned uv2 __attribute__((ext_vector_type(2)));
typedef float v2f __attribute__((ext_vector_type(2)));
typedef float v4f __attribute__((ext_vector_type(4)));
typedef __bf16 v8bf __attribute__((ext_vector_type(8)));

__device__ __forceinline__ float fexp2(float a) { return __builtin_amdgcn_exp2f(a); }

__device__ __forceinline__ float bpermf(int idx_bytes, float v) {
  return __int_as_float(__builtin_amdgcn_ds_bpermute(idx_bytes, __float_as_int(v)));
}

// (fallback kernel only)
__device__ __forceinline__ float xhalf_sum(float p) {
#if __has_builtin(__builtin_amdgcn_permlane32_swap)
  uv2 r = __builtin_amdgcn_permlane32_swap(__float_as_uint(p), __float_as_uint(p),
                                           false, false);
  return __uint_as_float(r[0]) + __uint_as_float(r[1]);
#else
  return p + bpermf((threadIdx.x ^ 32) << 2, p);
#endif
}

// pack two f32 -> 2xbf16 dword (RNE); no builtin on gfx950 (T12/m240)
__device__ __forceinline__ unsigned cvtpk(float lo, float hi) {
  unsigned r;
  asm("v_cvt_pk_bf16_f32 %0, %1, %2" : "=v"(r) : "v"(lo), "v"(hi));
  return r;
}

__device__ __forceinline__ v8bf frag_from(unsigned u0, unsigned u1, unsigned u2,
                                          unsigned u3) {
  uint4 uu = make_uint4(u0, u1, u2, u3);
  return __builtin_bit_cast(v8bf, uu);
}

// gx[b,t,g]: g<64  -> L2E*(x.w_ih[g] + b_ih[g] + b_hh[g])   (r,z pre-activation)
//            g>=64 -> 2*L2E*(x.w_ih[g] + b_ih[g])           (n x-side)
__global__ __launch_bounds__(256) void gx_pre(
    const float* __restrict__ x, const float* __restrict__ w_ih,
    const float* __restrict__ b_ih, const float* __restrict__ b_hh,
    const int* __restrict__ lengths, float* __restrict__ gx) {
  const size_t idx = (size_t)blockIdx.x * 256 + threadIdx.x;  // (b*T+t)*96+g
  const int g = (int)(idx % 96);
  const size_t bt = idx / 96;
  const int b = (int)(bt >> 12);
  const int t = (int)(bt & (TT - 1));
  if (t >= lengths[b]) return;
  const float* xp = x + bt * 6;
  float acc = (g < 64) ? (b_ih[g] + b_hh[g]) : b_ih[g];
#pragma unroll
  for (int i = 0; i < 6; ++i) acc = fmaf(w_ih[g * 6 + i], xp[i], acc);
  gx[idx] = (g < 64) ? (L2E * acc) : (2.0f * L2E * acc);
}

// One wave per batch element. The 96x32 matvec runs on the MATRIX pipe:
// D = A.B with A[m][k] = h[k] replicated over all m (8 bperm + 4 cvt_pk),
// B[k][n] = Wt (6 constant bf16 fragments, 24 VGPRs). D col = lane&15
// (m89-verified) puts y[j] at the lanes that need it; cndmask picks the
// j<16 / j>=16 half. k-slot layout risk cancels: A and B are packed with the
// SAME assumed (lane,e)->k bijection, so the k-sum is invariant to the HW's
// true k mapping. h stays fp32 across steps; only mfma inputs are bf16.
__global__ __launch_bounds__(64) __attribute__((amdgpu_waves_per_eu(1, 1)))
void gru_seq(const int* __restrict__ lengths, const float* __restrict__ w_hh,
             const float* __restrict__ b_hh, const float* __restrict__ gx,
             float* __restrict__ hbuf) {
  __shared__ alignas(16) float hring[2][32][32];  // buf, step, j = 8 KB

  const int b = blockIdx.x;
  const int l = threadIdx.x;
  const int j = l & 31;
  const int len = lengths[b];
  const int n_ = l & 15;        // B/D column this lane carries
  const int kb = (l >> 4) * 8;  // assumed k-slot base for this lane

  // 6 constant B fragments: B[k][n] = W[grow + jb + n][k] * scale (bf16)
  auto make_wfrag = [&](int grow, int jb, float scale) -> v8bf {
    const float* wrow = w_hh + (grow + jb + n_) * 32 + kb;
    unsigned u0 = cvtpk(wrow[0] * scale, wrow[1] * scale);
    unsigned u1 = cvtpk(wrow[2] * scale, wrow[3] * scale);
    unsigned u2 = cvtpk(wrow[4] * scale, wrow[5] * scale);
    unsigned u3 = cvtpk(wrow[6] * scale, wrow[7] * scale);
    return frag_from(u0, u1, u2, u3);
  };
  const v8bf fR0 = make_wfrag(0, 0, L2E),          fR1 = make_wfrag(0, 16, L2E);
  const v8bf fZ0 = make_wfrag(32, 0, L2E),         fZ1 = make_wfrag(32, 16, L2E);
  const v8bf fN0 = make_wfrag(64, 0, 2.0f * L2E),  fN1 = make_wfrag(64, 16, 2.0f * L2E);
  // n-gate hidden bias as the C operand (free accumulate)
  v4f cn0, cn1;
  {
    const float c0 = 2.0f * L2E * b_hh[64 + n_];
    const float c1 = 2.0f * L2E * b_hh[80 + n_];
    cn0 = v4f{c0, c0, c0, c0};
    cn1 = v4f{c1, c1, c1, c1};
  }
  const v4f zero4 = v4f{0.f, 0.f, 0.f, 0.f};
  const bool hiSel = ((l >> 4) & 1);  // j = l&31 >= 16 <=> use jb=16 result

  const float* gxb = gx + (size_t)b * TT * 96;
  float* hrow = hbuf + (size_t)b * TT * 32;
  const int bpbase = (l >> 4) << 5;  // byte index of h[kb]

  float h = 0.0f;
  int t = 0;

  // 4-deep gx prefetch slots (named scalars; static indexing)
  float g0r, g0z, g0n, g1r, g1z, g1n, g2r, g2z, g2n, g3r, g3z, g3n;
  {
    const int t1 = (1 < len) ? 1 : len - 1, t2 = (2 < len) ? 2 : len - 1,
              t3 = (3 < len) ? 3 : len - 1;
    const float *p0 = gxb, *p1 = gxb + (size_t)t1 * 96,
                *p2 = gxb + (size_t)t2 * 96, *p3 = gxb + (size_t)t3 * 96;
    g0r = p0[j]; g0z = p0[32 + j]; g0n = p0[64 + j];
    g1r = p1[j]; g1z = p1[32 + j]; g1n = p1[64 + j];
    g2r = p2[j]; g2z = p2[32 + j]; g2n = p2[64 + j];
    g3r = p3[j]; g3z = p3[32 + j]; g3n = p3[64 + j];
  }

  auto flush = [&](int base, int cnt) {
    const float4* src = (const float4*)(&hring[(base >> 5) & 1][0][0]);
    float4* dst = (float4*)(hrow + (size_t)base * 32);
    const int n4 = cnt * 8;
    for (int q = l; q < n4; q += 64) dst[q] = src[q];
  };

  auto step = [&](float& GR, float& GZ, float& GN) {
    const float xr_ = GR, xz_ = GZ, xn_ = GN;
    // refill this slot for t+4 (independent; max slack)
    {
      const int tp = (t + 4 < len) ? (t + 4) : (len - 1);
      const float* gp = gxb + (size_t)tp * 96;
      GR = gp[j]; GZ = gp[32 + j]; GN = gp[64 + j];
    }

    // A fragment: h[kb..kb+7] via 8 bperm + 4 cvt_pk (same k-order as B)
    const float p0 = bpermf(bpbase + 0, h),  p1 = bpermf(bpbase + 4, h);
    const float p2 = bpermf(bpbase + 8, h),  p3 = bpermf(bpbase + 12, h);
    const float p4 = bpermf(bpbase + 16, h), p5 = bpermf(bpbase + 20, h);
    const float p6 = bpermf(bpbase + 24, h), p7 = bpermf(bpbase + 28, h);
    const v8bf ha = frag_from(cvtpk(p0, p1), cvtpk(p2, p3),
                              cvtpk(p4, p5), cvtpk(p6, p7));

    // 6 independent MFMAs: full K=32 dot per gate-half
    const v4f yr0 = __builtin_amdgcn_mfma_f32_16x16x32_bf16(ha, fR0, zero4, 0, 0, 0);
    const v4f yr1 = __builtin_amdgcn_mfma_f32_16x16x32_bf16(ha, fR1, zero4, 0, 0, 0);
    const v4f yz0 = __builtin_amdgcn_mfma_f32_16x16x32_bf16(ha, fZ0, zero4, 0, 0, 0);
    const v4f yz1 = __builtin_amdgcn_mfma_f32_16x16x32_bf16(ha, fZ1, zero4, 0, 0, 0);
    const v4f yn0 = __builtin_amdgcn_mfma_f32_16x16x32_bf16(ha, fN0, cn0, 0, 0, 0);
    const v4f yn1 = __builtin_amdgcn_mfma_f32_16x16x32_bf16(ha, fN1, cn1, 0, 0, 0);

    const float yr = hiSel ? yr1[0] : yr0[0];
    const float yz = hiSel ? yz1[0] : yz0[0];
    const float hn = hiSel ? yn1[0] : yn0[0];  // incl. bhn via C

    const float r_ = __builtin_amdgcn_rcpf(1.0f + fexp2(-(yr + xr_)));
    const float z_ = __builtin_amdgcn_rcpf(1.0f + fexp2(-(yz + xz_)));
    const float ap = fmaf(r_, hn, xn_);
    const float q_ = __builtin_amdgcn_rcpf(1.0f + fexp2(-ap));
    const float nn = fmaf(2.0f, q_, -1.0f);
    h = fmaf(z_, h - nn, nn);

    hring[(t >> 5) & 1][t & 31][j] = h;  // duplicate halves write same value
    if ((t & 31) == 31) flush(t - 31, 32);
    ++t;
  };

  while (t + 4 <= len) {
    step(g0r, g0z, g0n);
    step(g1r, g1z, g1n);
    step(g2r, g2z, g2n);
    step(g3r, g3z, g3n);
  }
  if (t < len) step(g0r, g0z, g0n);
  if (t < len) step(g1r, g1z, g1n);
  if (t < len) step(g2r, g2z, g2n);

  const int rem = len & 31;
  if (rem) flush(len - rem, rem);
}

// out[b,t,:] = (t < len[b]) ? h[b,t,:] @ fc_w^T + fc_b : fc_b
__global__ __launch_bounds__(256) void fc_apply(
    const float* __restrict__ hbuf, const int* __restrict__ lengths,
    const float* __restrict__ fc_w, const float* __restrict__ fc_b,
    float* __restrict__ out) {
  const int idx = blockIdx.x * 256 + threadIdx.x;  // flattened (b,t)
  const int b = idx >> 12;
  const int t = idx & (TT - 1);
  const float fb0 = fc_b[0], fb1 = fc_b[1];
  float* op = out + (size_t)idx * 2;
  if (t >= lengths[b]) {
    op[0] = fb0;
    op[1] = fb1;
    return;
  }
  const float4* hp = (const float4*)(hbuf + (size_t)idx * 32);
  const float4* w0 = (const float4*)(fc_w);
  const float4* w1 = (const float4*)(fc_w + 32);
  float o0 = 0.f, o1 = 0.f;
#pragma unroll
  for (int q = 0; q < 8; ++q) {
    const float4 hv = hp[q], a = w0[q], c = w1[q];
    o0 += hv.x * a.x + hv.y * a.y + hv.z * a.z + hv.w * a.w;
    o1 += hv.x * c.x + hv.y * c.y + hv.z * c.z + hv.w * c.w;
  }
  op[0] = o0 + fb0;
  op[1] = o1 + fb1;
}

// Fallback (ws too small): self-contained single kernel (R6 structure).
__global__ __launch_bounds__(64) void gru_fallback(
    const float* __restrict__ x, const int* __restrict__ lengths,
    const float* __restrict__ w_ih, const float* __restrict__ w_hh,
    const float* __restrict__ b_ih, const float* __restrict__ b_hh,
    const float* __restrict__ fc_w, const float* __restrict__ fc_b,
    float* __restrict__ out) {
  const int b = blockIdx.x;
  const int l = threadIdx.x;
  const int j = l & 31;
  const int half = l >> 5;
  const int ko = half << 4;
  const int len = lengths[b];

  float wr[16], wz[16], wn[16];
#pragma unroll
  for (int k = 0; k < 16; ++k) wr[k] = w_hh[j * 32 + ko + k] * L2E;
#pragma unroll
  for (int k = 0; k < 16; ++k) wz[k] = w_hh[(32 + j) * 32 + ko + k] * L2E;
#pragma unroll
  for (int k = 0; k < 16; ++k) wn[k] = w_hh[(64 + j) * 32 + ko + k] * (2.0f * L2E);
  float wxr[6], wxz[6], wxn[6];
#pragma unroll
  for (int i = 0; i < 6; ++i) wxr[i] = w_ih[j * 6 + i] * (0.5f * L2E);
#pragma unroll
  for (int i = 0; i < 6; ++i) wxz[i] = w_ih[(32 + j) * 6 + i] * (0.5f * L2E);
#pragma unroll
  for (int i = 0; i < 6; ++i) wxn[i] = w_ih[(64 + j) * 6 + i] * (2.0f * L2E);
  const float br = (b_ih[j] + b_hh[j]) * (0.5f * L2E);
  const float bz = (b_ih[32 + j] + b_hh[32 + j]) * (0.5f * L2E);
  const float bxn = b_ih[64 + j] * (2.0f * L2E);
  const float bhn = b_hh[64 + j] * L2E;
  const float fcw = fc_w[half * 32 + j];
  const float fcb = fc_b[half];

  const float* xb = x + (size_t)b * (TT * 6);
  float* ob = out + (size_t)b * (TT * 2);
  const int bko = half << 6;
  float h = 0.0f;

  v2f cx[3], nx[3];
  {
    const v2f* xp = (const v2f*)xb;
    cx[0] = xp[0]; cx[1] = xp[1]; cx[2] = xp[2];
  }
  for (int t = 0; t < len; ++t) {
    const int tn = (t + 1 < len) ? (t + 1) : t;
    const v2f* xp = (const v2f*)(xb + tn * 6);
    nx[0] = xp[0]; nx[1] = xp[1]; nx[2] = xp[2];
    float xr = br, xz = bz, xn = bxn;
#pragma unroll
    for (int i = 0; i < 3; ++i) {
      const float c0 = cx[i][0], c1 = cx[i][1];
      xr = fmaf(wxr[2 * i], c0, xr); xr = fmaf(wxr[2 * i + 1], c1, xr);
      xz = fmaf(wxz[2 * i], c0, xz); xz = fmaf(wxz[2 * i + 1], c1, xz);
      xn = fmaf(wxn[2 * i], c0, xn); xn = fmaf(wxn[2 * i + 1], c1, xn);
    }
    float hbv[16];
#pragma unroll
    for (int k = 0; k < 16; ++k) hbv[k] = bpermf(bko + (k << 2), h);
    float ar0 = xr, ar1 = 0.f, az0 = xz, az1 = 0.f, an0 = bhn, an1 = 0.f;
#pragma unroll
    for (int k = 0; k < 8; ++k) {
      ar0 = fmaf(wr[k], hbv[k], ar0);
      ar1 = fmaf(wr[k + 8], hbv[k + 8], ar1);
      az0 = fmaf(wz[k], hbv[k], az0);
      az1 = fmaf(wz[k + 8], hbv[k + 8], az1);
      an0 = fmaf(wn[k], hbv[k], an0);
      an1 = fmaf(wn[k + 8], hbv[k + 8], an1);
    }
    const float sr = xhalf_sum(ar0 + ar1);
    const float r = __builtin_amdgcn_rcpf(1.0f + fexp2(-sr));
    const float sz = xhalf_sum(az0 + az1);
    const float z = __builtin_amdgcn_rcpf(1.0f + fexp2(-sz));
    const float hn = xhalf_sum(an0 + an1);
    const float ap = fmaf(r, hn, xn);
    const float qq = __builtin_amdgcn_rcpf(1.0f + fexp2(-ap));
    const float nn = fmaf(2.0f, qq, -1.0f);
    h = fmaf(z, h - nn, nn);
    float p = h * fcw;
    p += __shfl_xor(p, 1);
    p += __shfl_xor(p, 2);
    p += __shfl_xor(p, 4);
    p += __shfl_xor(p, 8);
    p += __shfl_xor(p, 16);
    if (j == 0) ob[t * 2 + half] = p + fcb;
#pragma unroll
    for (int i = 0; i < 3; ++i) cx[i] = nx[i];
  }
  const float fb0 = fc_b[0], fb1 = fc_b[1];
  for (int idx = len * 2 + l; idx < TT * 2; idx += 64)
    ob[idx] = (idx & 1) ? fb1 : fb0;
}

extern "C" void kernel_launch(void* const* d_in, const int* in_sizes, int n_in,
                              void* d_out, int out_size, void* d_ws, size_t ws_size,
                              hipStream_t stream) {
  const float* x       = (const float*)d_in[0];
  const int*   lengths = (const int*)d_in[1];
  const float* w_ih    = (const float*)d_in[2];
  const float* w_hh    = (const float*)d_in[3];
  const float* b_ih    = (const float*)d_in[4];
  const float* b_hh    = (const float*)d_in[5];
  const float* fc_w    = (const float*)d_in[6];
  const float* fc_b    = (const float*)d_in[7];
  float* outp = (float*)d_out;

  const size_t hbuf_elems = (size_t)BB * TT * 32;               // 64 MB
  const size_t gx_elems   = (size_t)BB * TT * 96;               // 192 MB
  const size_t need = (hbuf_elems + gx_elems) * sizeof(float);  // 256 MB
  if (ws_size >= need) {
    float* hbuf = (float*)d_ws;
    float* gx = (float*)d_ws + hbuf_elems;
    hipLaunchKernelGGL(gx_pre, dim3((BB * TT * 96) / 256), dim3(256), 0, stream,
                       x, w_ih, b_ih, b_hh, lengths, gx);
    hipLaunchKernelGGL(gru_seq, dim3(BB), dim3(64), 0, stream,
                       lengths, w_hh, b_hh, gx, hbuf);
    hipLaunchKernelGGL(fc_apply, dim3((BB * TT) / 256), dim3(256), 0, stream,
                       hbuf, lengths, fc_w, fc_b, outp);
  } else {
    hipLaunchKernelGGL(gru_fallback, dim3(BB), dim3(64), 0, stream,
                       x, lengths, w_ih, w_hh, b_ih, b_hh, fc_w, fc_b, outp);
  }
}